// Round 1
// baseline (221.313 us; speedup 1.0000x reference)
//
#include <hip/hip_runtime.h>
#include <math.h>

#define OUTSZ 7
#define SRATE 2

// Problem constants (fixed by setup_inputs)
#define B_ 2
#define C_ 256
#define R_ 256

__global__ __launch_bounds__(256) void roi_pooler_kernel(
    const float* __restrict__ f0, const float* __restrict__ f1,
    const float* __restrict__ f2, const float* __restrict__ f3,
    const float* __restrict__ boxes, float* __restrict__ out)
{
    const int total = B_ * R_ * C_ * OUTSZ * OUTSZ;
    int idx = blockIdx.x * blockDim.x + threadIdx.x;
    if (idx >= total) return;

    int ox = idx % OUTSZ;
    int oy = (idx / OUTSZ) % OUTSZ;
    int c  = (idx / (OUTSZ * OUTSZ)) % C_;
    int n  = idx / (OUTSZ * OUTSZ * C_);
    int b  = n / R_;

    // ---- per-ROI setup (recomputed per thread; ~50 flops) ----
    const float* bx = boxes + (size_t)n * 4;
    float x1 = bx[0], y1 = bx[1], x2 = bx[2], y2 = bx[3];
    float area = (x2 - x1) * (y2 - y1);
    float lf = floorf(4.0f + log2f(sqrtf(area) / 224.0f + 1e-8f));
    lf = fminf(fmaxf(lf, 2.0f), 5.0f);
    int lvl = (int)lf - 2;

    const float scales[4] = {0.25f, 0.125f, 0.0625f, 0.03125f};
    const int   sizes[4]  = {200, 100, 50, 25};
    float scale = scales[lvl];
    int   HW    = sizes[lvl];
    const float* fptr;
    switch (lvl) {
        case 0:  fptr = f0; break;
        case 1:  fptr = f1; break;
        case 2:  fptr = f2; break;
        default: fptr = f3; break;
    }

    float fx1 = x1 * scale, fy1 = y1 * scale;
    float fx2 = x2 * scale, fy2 = y2 * scale;
    float roi_w = fmaxf(fx2 - fx1, 1.0f);
    float roi_h = fmaxf(fy2 - fy1, 1.0f);
    float bw = roi_w / OUTSZ;
    float bh = roi_h / OUTSZ;

    const float* plane = fptr + ((size_t)b * C_ + c) * (size_t)(HW * HW);
    float lim = (float)HW;
    float cap = lim - 1.0f;

    float acc = 0.0f;
    #pragma unroll
    for (int sy = 0; sy < SRATE; sy++) {
        float yc = fy1 + bh * ((float)oy + ((float)sy + 0.5f) / SRATE);
        // _prep for y  (torchvision aligned=False semantics)
        bool  vy  = (yc > -1.0f) && (yc < lim);
        float ccy = fmaxf(yc, 0.0f);
        float lowy = floorf(ccy);
        bool  ey  = lowy >= cap;
        lowy = fminf(lowy, cap);
        float highy = fminf(lowy + 1.0f, cap);
        float wfy = ey ? 0.0f : (ccy - lowy);
        int yl = (int)lowy, yh = (int)highy;

        #pragma unroll
        for (int sx = 0; sx < SRATE; sx++) {
            float xc = fx1 + bw * ((float)ox + ((float)sx + 0.5f) / SRATE);
            bool  vx  = (xc > -1.0f) && (xc < lim);
            float ccx = fmaxf(xc, 0.0f);
            float lowx = floorf(ccx);
            bool  ex  = lowx >= cap;
            lowx = fminf(lowx, cap);
            float highx = fminf(lowx + 1.0f, cap);
            float wfx = ex ? 0.0f : (ccx - lowx);
            int xl = (int)lowx, xh = (int)highx;

            if (vy && vx) {
                float v00 = plane[yl * HW + xl];
                float v01 = plane[yl * HW + xh];
                float v10 = plane[yh * HW + xl];
                float v11 = plane[yh * HW + xh];
                acc += (1.0f - wfy) * (1.0f - wfx) * v00
                     + (1.0f - wfy) * wfx          * v01
                     + wfy          * (1.0f - wfx) * v10
                     + wfy          * wfx          * v11;
            }
        }
    }

    out[idx] = acc * (1.0f / (SRATE * SRATE));
}

extern "C" void kernel_launch(void* const* d_in, const int* in_sizes, int n_in,
                              void* d_out, int out_size, void* d_ws, size_t ws_size,
                              hipStream_t stream) {
    const float* f0    = (const float*)d_in[0];
    const float* f1    = (const float*)d_in[1];
    const float* f2    = (const float*)d_in[2];
    const float* f3    = (const float*)d_in[3];
    const float* boxes = (const float*)d_in[4];
    float* out = (float*)d_out;

    const int total = B_ * R_ * C_ * OUTSZ * OUTSZ;  // 6,422,528
    int block = 256;
    int grid = (total + block - 1) / block;
    roi_pooler_kernel<<<grid, block, 0, stream>>>(f0, f1, f2, f3, boxes, out);
}